// Round 19
// baseline (225.708 us; speedup 1.0000x reference)
//
#include <hip/hip_runtime.h>
#include <hip/hip_bf16.h>

#define B 16
#define L 64
#define P 1024
#define V 64
#define Q 16
#define LN64 4.158883083359672f

#define CHBC 16           // p per k_bc block
#define NCH_BC (P / CHBC) // 64

typedef unsigned short ushort8_t __attribute__((ext_vector_type(8)));
typedef __attribute__((ext_vector_type(8))) short bf16x8;
typedef __attribute__((ext_vector_type(4))) float f32x4;

typedef const __attribute__((address_space(1))) void* gld_gptr_t;
typedef __attribute__((address_space(3))) void* gld_lptr_t;

static __device__ __forceinline__ float bf2f(ushort u) {
    return __uint_as_float(((unsigned int)u) << 16);
}
static __device__ __forceinline__ ushort f2bf(float f) {
    unsigned int x = __float_as_uint(f);
    unsigned int r = (x + 0x7fffu + ((x >> 16) & 1u)) >> 16;
    return (ushort)r;
}
static __device__ __forceinline__ unsigned pk2(float lo, float hi) {
    return (unsigned)f2bf(lo) | ((unsigned)f2bf(hi) << 16);
}

static __device__ __forceinline__ float wsum64(float v) {
#pragma unroll
    for (int m = 32; m > 0; m >>= 1) v += __shfl_xor(v, m, 64);
    return v;
}
static __device__ __forceinline__ float wmax64(float v) {
#pragma unroll
    for (int m = 32; m > 0; m >>= 1) v = fmaxf(v, __shfl_xor(v, m, 64));
    return v;
}

union FragU { uint4 u; bf16x8 s; };

// ---------------------------------------------------------------------------
// K_uhat v19: v18 (swapped-operand MFMA, sv layout, coalesced stores) with
// stores HOISTED OUT of the K-loop. Theory: the persistent ~1.6-2.2 TB/s
// producer wall is HBM read/write stream MIXING (every reference point is
// unidirectional: fillBuffer 6.9 TB/s pure-write, k_bc phase-1 ~5.8 TB/s
// pure-read; v1..v18 all interleaved 4KB reads with 2KB writes at ~100ns
// grain). v19's loop is pure stage->ds_read->MFMA; outputs live in 64 VGPR
// (uoA/uoB[8], literal indices only); one terminal burst writes uhat + sp0.
// Per-block direction grains become ~10us. Waits: stage-only queue, depth-2,
// 3-slot ring (no slot race): steady vmcnt(4); tail vmcnt(0).
// VGPR ~145 < 168 cap (launch_bounds(256,3), 48KB LDS -> 3 blocks/CU).
// ---------------------------------------------------------------------------
__global__ __launch_bounds__(256, 3) void k_uhat(const float* __restrict__ Wt,
                                                 const float* __restrict__ x,
                                                 ushort* __restrict__ uhat,
                                                 float* __restrict__ sp0) {
    const int t = threadIdx.x;
    const int w = t >> 6;
    const int lane = t & 63;
    const int kb = lane >> 4;     // k-octet / D row-quad (sv high bits)
    const int cc = lane & 15;     // D col = b ; A row = v low bits
    const int ch = blockIdx.x;    // p-chunk of 32
    const int l = blockIdx.y;
    const int p0 = ch * 32;

    __shared__ __align__(16) char smem[49152];  // xstage 16KB, then 4x12KB rings
    unsigned int* xstage = (unsigned int*)smem; // [32 p][32 ln][4]

#pragma unroll
    for (int i = 0; i < 16; ++i) {
        const int e = i * 256 + t;        // 4096 entries
        const int pp = e >> 7, ln = (e >> 2) & 31, m = e & 3;
        const int b = ln & 15, qb = (ln >> 4) * 8;
        const float2 xv = *reinterpret_cast<const float2*>(
            x + ((size_t)b * P + p0 + pp) * Q + qb + 2 * m);
        xstage[e] = pk2(xv.x, xv.y);
    }
    __syncthreads();

    uint4 af[8];                  // x B-frags (zeros for lane>=32 -> k>=16)
#pragma unroll
    for (int i = 0; i < 8; ++i) {
        if (lane < 32)
            af[i] = *reinterpret_cast<const uint4*>(
                smem + ((size_t)(w * 8 + i) * 32 + lane) * 16);
        else
            af[i] = (uint4){0u, 0u, 0u, 0u};
    }
    __syncthreads();   // xstage dead; rings may overwrite smem

    char* ring = smem + w * 12288;        // wave-private 3 x 4 KB
    const int sperm = (lane & ~3) | ((lane & 3) ^ ((lane >> 3) & 3));
    const char* gW = (const char*)(Wt + ((size_t)l * P + p0 + w * 8) * (V * Q))
                     + (size_t)sperm * 16;
    const int xk = (cc >> 1) & 3;         // read-side chunk XOR

    f32x4 cacc0 = {0.f, 0.f, 0.f, 0.f}, cacc1 = {0.f, 0.f, 0.f, 0.f};
    f32x4 cacc2 = {0.f, 0.f, 0.f, 0.f}, cacc3 = {0.f, 0.f, 0.f, 0.f};
    uint4 uoA[8], uoB[8];                 // deferred output (64 VGPR)

#define STAGE(i_)                                                             \
    {                                                                         \
        const char* s_ = gW + (size_t)(i_) * 4096;                            \
        char* d_ = ring + ((i_) % 3) * 4096;                                  \
        __builtin_amdgcn_global_load_lds((gld_gptr_t)(s_ + 0),                \
                                         (gld_lptr_t)(d_ + 0), 16, 0, 0);     \
        __builtin_amdgcn_global_load_lds((gld_gptr_t)(s_ + 1024),             \
                                         (gld_lptr_t)(d_ + 1024), 16, 0, 0);  \
        __builtin_amdgcn_global_load_lds((gld_gptr_t)(s_ + 2048),             \
                                         (gld_lptr_t)(d_ + 2048), 16, 0, 0);  \
        __builtin_amdgcn_global_load_lds((gld_gptr_t)(s_ + 3072),             \
                                         (gld_lptr_t)(d_ + 3072), 16, 0, 0);  \
    }

// A-frag = W rows v = g*16 + cc, k-octet kb (kb>=2 -> zero, covered by x=0)
#define WFRAG(g_, dst_)                                                       \
    {                                                                         \
        if (lane < 32) {                                                      \
            const char* rb_ = ring + (slot_) * 4096 + (cc + 16 * (g_)) * 64;  \
            const float4 f0 =                                                 \
                *(const float4*)(rb_ + (((2 * kb + 0) ^ xk) << 4));           \
            const float4 f1 =                                                 \
                *(const float4*)(rb_ + (((2 * kb + 1) ^ xk) << 4));           \
            dst_.u = (uint4){pk2(f0.x, f0.y), pk2(f0.z, f0.w),                \
                             pk2(f1.x, f1.y), pk2(f1.z, f1.w)};               \
        } else {                                                              \
            dst_.u = (uint4){0u, 0u, 0u, 0u};                                 \
        }                                                                     \
    }

#define MMG(g_, cacc_, u_)                                                    \
    {                                                                         \
        FragU wf_;                                                            \
        WFRAG(g_, wf_);                                                       \
        f32x4 d_ = __builtin_amdgcn_mfma_f32_16x16x32_bf16(wf_.s, bx_.s,      \
                                                           cacc_, 0, 0, 0);   \
        u_ = d_ - cacc_;                                                      \
        cacc_ = d_;                                                           \
    }

#define COMPUTE(i_)                                                           \
    {                                                                         \
        const int slot_ = (i_) % 3;                                           \
        FragU bx_; bx_.u = af[i_];                                            \
        f32x4 u0_, u1_, u2_, u3_;                                             \
        MMG(0, cacc0, u0_);                                                   \
        MMG(1, cacc1, u1_);                                                   \
        MMG(2, cacc2, u2_);                                                   \
        MMG(3, cacc3, u3_);                                                   \
        uoA[i_].x = pk2(u0_[0], u1_[0]); uoA[i_].y = pk2(u2_[0], u3_[0]);     \
        uoA[i_].z = pk2(u0_[1], u1_[1]); uoA[i_].w = pk2(u2_[1], u3_[1]);     \
        uoB[i_].x = pk2(u0_[2], u1_[2]); uoB[i_].y = pk2(u2_[2], u3_[2]);     \
        uoB[i_].z = pk2(u0_[3], u1_[3]); uoB[i_].w = pk2(u2_[3], u3_[3]);     \
    }

#define WAITV(N)                                                              \
    asm volatile("s_waitcnt vmcnt(" #N ")" ::: "memory");                     \
    __builtin_amdgcn_sched_barrier(0);

    STAGE(0); STAGE(1);
    WAITV(4); STAGE(2); COMPUTE(0);
    WAITV(4); STAGE(3); COMPUTE(1);
    WAITV(4); STAGE(4); COMPUTE(2);
    WAITV(4); STAGE(5); COMPUTE(3);
    WAITV(4); STAGE(6); COMPUTE(4);
    WAITV(4); STAGE(7); COMPUTE(5);
    WAITV(4); COMPUTE(6);
    WAITV(0); COMPUTE(7);

    // terminal write burst: uhat (16 x 1KB-coalesced wave stores) + sp0
#pragma unroll
    for (int i = 0; i < 8; ++i) {
        const int p_ = p0 + w * 8 + i;
        ushort* ub_ = uhat + (((size_t)l * P + p_) * B + cc) * V + kb * 16;
        *reinterpret_cast<uint4*>(ub_) = uoA[i];
        *reinterpret_cast<uint4*>(ub_ + 8) = uoB[i];
    }
    {
        float* sb = sp0 + (((size_t)l * 128 + ch * 4 + w) * 16 + cc) * 64 + kb * 16;
        float4 q0 = {cacc0[0], cacc1[0], cacc2[0], cacc3[0]};
        float4 q1 = {cacc0[1], cacc1[1], cacc2[1], cacc3[1]};
        float4 q2 = {cacc0[2], cacc1[2], cacc2[2], cacc3[2]};
        float4 q3 = {cacc0[3], cacc1[3], cacc2[3], cacc3[3]};
        *reinterpret_cast<float4*>(sb + 0) = q0;
        *reinterpret_cast<float4*>(sb + 4) = q1;
        *reinterpret_cast<float4*>(sb + 8) = q2;
        *reinterpret_cast<float4*>(sb + 12) = q3;
    }
#undef STAGE
#undef WFRAG
#undef MMG
#undef COMPUTE
#undef WAITV
}

// ---------------------------------------------------------------------------
// K_v: generic chunk-reduce + squash (sv space). unperm=1 -> write true-v.
// ---------------------------------------------------------------------------
__global__ __launch_bounds__(256) void k_v(const float* __restrict__ sp,
                                           size_t cb, size_t cl, size_t cs,
                                           int nch, float scale, int unperm,
                                           float* __restrict__ vout,
                                           float* __restrict__ norms) {
    const int b = blockIdx.y;
    const int w = threadIdx.x >> 6, lane = threadIdx.x & 63;
    const int l = blockIdx.x * 4 + w;
    const float* p = sp + cb * b + cl * l + lane;
    float s = 0.f;
#pragma unroll 8
    for (int ch = 0; ch < nch; ++ch) s += p[(size_t)ch * cs];
    s *= scale;
    float sq = wsum64(s * s);
    float f = sqrtf(sq) / (1.0f + sq);
    const int vi = unperm ? ((lane & 3) * 16 + (lane >> 4) * 4 + ((lane >> 2) & 3))
                          : lane;
    vout[((size_t)b * L + l) * V + vi] = s * f;
    if (norms && lane == 0) norms[b * L + l] = sq / (1.0f + sq);
}

// ---------------------------------------------------------------------------
// K_bc: block = (ch of 16 p, b), 512 threads. u tile in REGISTERS.
// uhat layout [l][p][b][sv]; all v-space math in sv space (invariant).
// ---------------------------------------------------------------------------
__global__ __launch_bounds__(512, 4) void k_bc(const ushort* __restrict__ uhat,
                                               const float* __restrict__ vv,
                                               float* __restrict__ bbuf,
                                               float* __restrict__ sp,
                                               float* __restrict__ Tsum,
                                               int add_prev, int do_T) {
    const int ch = blockIdx.x, b = blockIdx.y;
    const int p0 = ch * CHBC;
    const int t = threadIdx.x;
    const int w = t >> 6, lane = t & 63;
    const int pl8 = lane >> 3;
    const int vg8 = lane & 7;
    const int l0 = w * 8;

    __shared__ float vsh[L][V];
    __shared__ float bl[CHBC][L + 1];
    __shared__ float twv[8];

    {
        const float4* vvp = reinterpret_cast<const float4*>(vv + (size_t)b * L * V);
        float4* vshp = reinterpret_cast<float4*>(&vsh[0][0]);
#pragma unroll
        for (int i = 0; i < 2; ++i) vshp[t + i * 512] = vvp[t + i * 512];
    }

    const size_t LSTR = (size_t)P * B * V;   // l stride
    ushort8_t ur[8][2];
    {
        const ushort* ubase = uhat + (((size_t)l0 * P + p0 + pl8) * B + b) * V + vg8 * 8;
#pragma unroll
        for (int li = 0; li < 8; ++li) {
#pragma unroll
            for (int ph = 0; ph < 2; ++ph)
                ur[li][ph] = *reinterpret_cast<const ushort8_t*>(
                    ubase + (size_t)li * LSTR + (size_t)ph * 8 * B * V);
        }
    }
    __syncthreads();

#pragma unroll
    for (int li = 0; li < 8; ++li) {
        const int l = l0 + li;
        const float4 va = *reinterpret_cast<const float4*>(&vsh[l][vg8 * 8]);
        const float4 vb = *reinterpret_cast<const float4*>(&vsh[l][vg8 * 8 + 4]);
#pragma unroll
        for (int ph = 0; ph < 2; ++ph) {
            float d;
            d = bf2f(ur[li][ph][0]) * va.x;
            d = fmaf(bf2f(ur[li][ph][1]), va.y, d);
            d = fmaf(bf2f(ur[li][ph][2]), va.z, d);
            d = fmaf(bf2f(ur[li][ph][3]), va.w, d);
            d = fmaf(bf2f(ur[li][ph][4]), vb.x, d);
            d = fmaf(bf2f(ur[li][ph][5]), vb.y, d);
            d = fmaf(bf2f(ur[li][ph][6]), vb.z, d);
            d = fmaf(bf2f(ur[li][ph][7]), vb.w, d);
            d += __shfl_xor(d, 1, 64);
            d += __shfl_xor(d, 2, 64);
            d += __shfl_xor(d, 4, 64);
            if (vg8 == 0) bl[ph * 8 + pl8][l] = d;
        }
    }
    __syncthreads();

    float tloc = 0.f;
#pragma unroll
    for (int pi = 0; pi < 2; ++pi) {
        const int pli = w * 2 + pi;
        const int p = p0 + pli;
        float bv = bl[pli][lane];
        float* bp = bbuf + ((size_t)b * P + p) * L;
        if (add_prev) bv += bp[lane];
        bp[lane] = bv;
        float m = wmax64(bv);
        float e = __expf(bv - m);
        float ssum = wsum64(e);
        float cc = e / ssum;
        bl[pli][lane] = cc;
        if (do_T) tloc += cc * __logf(64.0f * (cc + 1e-12f));
    }
    if (do_T) {
        float dsum = wsum64(tloc);
        if (lane == 0) twv[w] = dsum;
    }
    __syncthreads();
    if (do_T && t == 0) {
        float s8 = twv[0] + twv[1] + twv[2] + twv[3] +
                   twv[4] + twv[5] + twv[6] + twv[7];
        atomicAdd(Tsum, s8 * (1.0f / LN64));
    }

    float* spb = sp + (size_t)(b * NCH_BC + ch) * L * V;
#pragma unroll
    for (int li = 0; li < 8; ++li) {
        const int l = l0 + li;
        const float cA = bl[pl8][l];
        const float cB = bl[8 + pl8][l];
        float4 pa, pb;
        pa.x = cA * bf2f(ur[li][0][0]) + cB * bf2f(ur[li][1][0]);
        pa.y = cA * bf2f(ur[li][0][1]) + cB * bf2f(ur[li][1][1]);
        pa.z = cA * bf2f(ur[li][0][2]) + cB * bf2f(ur[li][1][2]);
        pa.w = cA * bf2f(ur[li][0][3]) + cB * bf2f(ur[li][1][3]);
        pb.x = cA * bf2f(ur[li][0][4]) + cB * bf2f(ur[li][1][4]);
        pb.y = cA * bf2f(ur[li][0][5]) + cB * bf2f(ur[li][1][5]);
        pb.z = cA * bf2f(ur[li][0][6]) + cB * bf2f(ur[li][1][6]);
        pb.w = cA * bf2f(ur[li][0][7]) + cB * bf2f(ur[li][1][7]);
#pragma unroll
        for (int m = 8; m <= 32; m <<= 1) {
            pa.x += __shfl_xor(pa.x, m, 64);
            pa.y += __shfl_xor(pa.y, m, 64);
            pa.z += __shfl_xor(pa.z, m, 64);
            pa.w += __shfl_xor(pa.w, m, 64);
            pb.x += __shfl_xor(pb.x, m, 64);
            pb.y += __shfl_xor(pb.y, m, 64);
            pb.z += __shfl_xor(pb.z, m, 64);
            pb.w += __shfl_xor(pb.w, m, 64);
        }
        if (pl8 == 0) {
            *reinterpret_cast<float4*>(spb + (size_t)l * V + vg8 * 8) = pa;
            *reinterpret_cast<float4*>(spb + (size_t)l * V + vg8 * 8 + 4) = pb;
        }
    }
}

// ---------------------------------------------------------------------------
// K_final: T and D. One block, 64 threads (lane = l).
// ---------------------------------------------------------------------------
__global__ void k_final(const float* __restrict__ Tsum,
                        const float* __restrict__ norms,
                        float* __restrict__ out) {
    const int lane = threadIdx.x & 63;
    float n[B];
    float sum = 0.f;
#pragma unroll
    for (int b = 0; b < B; ++b) { n[b] = norms[b * L + lane]; sum += n[b]; }
    const float mean = sum * (1.0f / B);
    float var = 0.f;
#pragma unroll
    for (int b = 0; b < B; ++b) { float d = n[b] - mean; var = fmaf(d, d, var); }
    var *= (1.0f / B);
    float sd = sqrtf(var);
    float D = wmax64(sd);
    if (lane == 0) {
        out[B * L * V] = Tsum[0] * (1.0f / (B * P));
        out[B * L * V + 1] = D;
    }
}

extern "C" void kernel_launch(void* const* d_in, const int* in_sizes, int n_in,
                              void* d_out, int out_size, void* d_ws, size_t ws_size,
                              hipStream_t stream) {
    const float* x = (const float*)d_in[0];   // (B,P,Q)
    const float* W = (const float*)d_in[1];   // (L,P,V,Q)
    float* out = (float*)d_out;               // v (B,L,V) then T, D

    char* ws = (char*)d_ws;
    ushort* uhat = (ushort*)ws;                        // [l][p][b][sv] bf16 = 128 MB
    size_t off = (size_t)B * L * P * V * 2;
    float* spbuf = (float*)(ws + off);                 // 32 MB region:
    // sp0 [l][128][16][64] (32 MB, iter-0) overlaps sp [b][64][l][v] (16 MB)
    off += (size_t)64 * 128 * 16 * 64 * 4;
    float* vbuf  = (float*)(ws + off); off += (size_t)B * L * V * 4;
    float* bbuf  = (float*)(ws + off); off += (size_t)B * P * L * 4;   // 4 MB
    float* norms = (float*)(ws + off); off += (size_t)B * L * 4;
    float* Tsum  = (float*)(ws + off); off += 256;

    hipMemsetAsync(Tsum, 0, sizeof(float), stream);

    // u_hat: read-only K-loop, terminal write burst + fused s0
    hipLaunchKernelGGL(k_uhat, dim3(32, 64), dim3(256), 0, stream, W, x, uhat, spbuf);
    // v0 = squash((1/64) * reduce sp0)   (sv space)
    hipLaunchKernelGGL(k_v, dim3(L / 4, B), dim3(256), 0, stream,
                       spbuf, (size_t)64, (size_t)131072, (size_t)1024, 128,
                       1.0f / 64.0f, 0, vbuf, (float*)nullptr);
    // b1 = v0.u ; c1 ; partial s1 -> sp[b][ch][l][sv]
    hipLaunchKernelGGL(k_bc, dim3(NCH_BC, B), dim3(512), 0, stream,
                       uhat, vbuf, bbuf, spbuf, Tsum, 0, 0);
    // v1 (sv space)
    hipLaunchKernelGGL(k_v, dim3(L / 4, B), dim3(256), 0, stream,
                       spbuf, (size_t)NCH_BC * L * V, (size_t)V, (size_t)L * V,
                       NCH_BC, 1.0f, 0, vbuf, (float*)nullptr);
    // b2 = b1 + v1.u ; c2 ; T partials ; partial s2
    hipLaunchKernelGGL(k_bc, dim3(NCH_BC, B), dim3(512), 0, stream,
                       uhat, vbuf, bbuf, spbuf, Tsum, 1, 1);
    // v2 -> out (un-permuted to true v), norms
    hipLaunchKernelGGL(k_v, dim3(L / 4, B), dim3(256), 0, stream,
                       spbuf, (size_t)NCH_BC * L * V, (size_t)V, (size_t)L * V,
                       NCH_BC, 1.0f, 1, out, norms);
    hipLaunchKernelGGL(k_final, dim3(1), dim3(64), 0, stream, Tsum, norms, out);
}

// Round 20
// 222.385 us; speedup vs baseline: 1.0149x; 1.0149x over previous
//
#include <hip/hip_runtime.h>
#include <hip/hip_bf16.h>

#define B 16
#define L 64
#define P 1024
#define V 64
#define Q 16
#define LN64 4.158883083359672f

#define CHBC 16           // p per k_bc block
#define NCH_BC (P / CHBC) // 64

typedef unsigned short ushort8_t __attribute__((ext_vector_type(8)));
typedef __attribute__((ext_vector_type(8))) short bf16x8;
typedef __attribute__((ext_vector_type(4))) float f32x4;

static __device__ __forceinline__ float bf2f(ushort u) {
    return __uint_as_float(((unsigned int)u) << 16);
}
static __device__ __forceinline__ ushort f2bf(float f) {
    unsigned int x = __float_as_uint(f);
    unsigned int r = (x + 0x7fffu + ((x >> 16) & 1u)) >> 16;
    return (ushort)r;
}
static __device__ __forceinline__ unsigned pk2(float lo, float hi) {
    return (unsigned)f2bf(lo) | ((unsigned)f2bf(hi) << 16);
}

static __device__ __forceinline__ float wsum64(float v) {
#pragma unroll
    for (int m = 32; m > 0; m >>= 1) v += __shfl_xor(v, m, 64);
    return v;
}
static __device__ __forceinline__ float wmax64(float v) {
#pragma unroll
    for (int m = 32; m > 0; m >>= 1) v = fmaxf(v, __shfl_xor(v, m, 64));
    return v;
}

union FragU { uint4 u; bf16x8 s; };

// ---------------------------------------------------------------------------
// K_uhat v20: REG-DIRECT COALESCED loads (k_bc's exact load mechanics) + MFMA.
// The one untested combination: v2-v9 were reg-direct but stride-64
// uncoalesced; v10-v19 coalesced but via global_load_lds+LDS ring (1M bank
// conflicts, LDS round-trip). k_bc (5.8 TB/s) is reg-direct AND coalesced.
// Trick: x B-frag is zero for k>=16, so A upper half-wave is a don't-care ->
// load TWO p per instruction (lanes 0-31 = p_even as k0..15, lanes 32-63 =
// p_odd as k16..31; 2x 1KB contiguous regions per instr) and select with two
// B-frag variants (afe: x in k<16; afo: x in k>=16; zeros elsewhere; bf16
// zero products are exact -> arithmetic bit-identical to v18).
// No LDS for W at all. Per wave: 4 p-pairs, 8 float4 loads/pair, depth-2
// pipeline; waits by exact replay: 8, 12, 12, 4. sv-layout stores (v18) and
// fused s0 unchanged. ~145 VGPR @ launch_bounds(256,3); LDS 16 KB.
// ---------------------------------------------------------------------------
__global__ __launch_bounds__(256, 3) void k_uhat(const float* __restrict__ Wt,
                                                 const float* __restrict__ x,
                                                 ushort* __restrict__ uhat,
                                                 float* __restrict__ sp0) {
    const int t = threadIdx.x;
    const int w = t >> 6;
    const int lane = t & 63;
    const int kb = lane >> 4;     // k-octet (0..3); kb>=2 -> p_odd role
    const int cc = lane & 15;     // A row (v low) / D col (b)
    const int ch = blockIdx.x;    // p-chunk of 32
    const int l = blockIdx.y;
    const int p0 = ch * 32;

    __shared__ unsigned int xstage[32][32][4];   // 16 KB packed-bf16 x

#pragma unroll
    for (int i = 0; i < 16; ++i) {
        const int e = i * 256 + t;        // 4096 entries
        const int pp = e >> 7, ln = (e >> 2) & 31, m = e & 3;
        const int b = ln & 15, qb = (ln >> 4) * 8;
        const float2 xv = *reinterpret_cast<const float2*>(
            x + ((size_t)b * P + p0 + pp) * Q + qb + 2 * m);
        xstage[pp][ln][m] = pk2(xv.x, xv.y);
    }
    __syncthreads();

    // B-frag variants per pair: afe (x in k<16), afo (x in k>=16)
    uint4 afe[4], afo[4];
#pragma unroll
    for (int i = 0; i < 4; ++i) {
        if (lane < 32)
            afe[i] = *reinterpret_cast<const uint4*>(&xstage[w * 8 + 2 * i][lane][0]);
        else
            afe[i] = (uint4){0u, 0u, 0u, 0u};
        if (lane >= 32)
            afo[i] = *reinterpret_cast<const uint4*>(&xstage[w * 8 + 2 * i + 1][lane - 32][0]);
        else
            afo[i] = (uint4){0u, 0u, 0u, 0u};
    }

    const float* gW = Wt + ((size_t)l * P + p0 + w * 8) * (V * Q);
    // per-lane base within pair: p_loc = 2i + (kb>>1); row v = g*16+cc; q-octet kb&1
    const float* lb = gW + (size_t)(kb >> 1) * (V * Q) + cc * Q + (kb & 1) * 8;

    f32x4 cacc0 = {0.f, 0.f, 0.f, 0.f}, cacc1 = {0.f, 0.f, 0.f, 0.f};
    f32x4 cacc2 = {0.f, 0.f, 0.f, 0.f}, cacc3 = {0.f, 0.f, 0.f, 0.f};
    float4 wl[2][8];

#define LOADP(i_, s_)                                                         \
    {                                                                         \
        const float* bp_ = lb + (size_t)(2 * (i_)) * (V * Q);                 \
        _Pragma("unroll")                                                     \
        for (int g_ = 0; g_ < 4; ++g_) {                                      \
            wl[s_][2 * g_ + 0] = *(const float4*)(bp_ + g_ * 256);            \
            wl[s_][2 * g_ + 1] = *(const float4*)(bp_ + g_ * 256 + 4);        \
        }                                                                     \
    }

#define ONEG(g_, s_, cacc_, ue_, uo_)                                         \
    {                                                                         \
        FragU wf_;                                                            \
        const float4 f0_ = wl[s_][2 * g_ + 0];                                \
        const float4 f1_ = wl[s_][2 * g_ + 1];                                \
        wf_.u = (uint4){pk2(f0_.x, f0_.y), pk2(f0_.z, f0_.w),                 \
                        pk2(f1_.x, f1_.y), pk2(f1_.z, f1_.w)};                \
        f32x4 De_ = __builtin_amdgcn_mfma_f32_16x16x32_bf16(wf_.s, axe_.s,    \
                                                            cacc_, 0, 0, 0);  \
        ue_ = De_ - cacc_;                                                    \
        f32x4 Do_ = __builtin_amdgcn_mfma_f32_16x16x32_bf16(wf_.s, axo_.s,    \
                                                            De_, 0, 0, 0);    \
        uo_ = Do_ - De_;                                                      \
        cacc_ = Do_;                                                          \
    }

#define STOREU(u0_, u1_, u2_, u3_, p_)                                        \
    {                                                                         \
        uint4 A_, Bv_;                                                        \
        A_.x = pk2(u0_[0], u1_[0]); A_.y = pk2(u2_[0], u3_[0]);               \
        A_.z = pk2(u0_[1], u1_[1]); A_.w = pk2(u2_[1], u3_[1]);               \
        Bv_.x = pk2(u0_[2], u1_[2]); Bv_.y = pk2(u2_[2], u3_[2]);             \
        Bv_.z = pk2(u0_[3], u1_[3]); Bv_.w = pk2(u2_[3], u3_[3]);             \
        ushort* ub_ = uhat + (((size_t)l * P + (p_)) * B + cc) * V + kb * 16; \
        *reinterpret_cast<uint4*>(ub_) = A_;                                  \
        *reinterpret_cast<uint4*>(ub_ + 8) = Bv_;                             \
    }

#define COMPUTEP(i_, s_)                                                      \
    {                                                                         \
        FragU axe_; axe_.u = afe[i_];                                         \
        FragU axo_; axo_.u = afo[i_];                                         \
        f32x4 ue0_, ue1_, ue2_, ue3_, uo0_, uo1_, uo2_, uo3_;                 \
        ONEG(0, s_, cacc0, ue0_, uo0_);                                       \
        ONEG(1, s_, cacc1, ue1_, uo1_);                                       \
        ONEG(2, s_, cacc2, ue2_, uo2_);                                       \
        ONEG(3, s_, cacc3, ue3_, uo3_);                                       \
        const int pe_ = p0 + w * 8 + 2 * (i_);                                \
        STOREU(ue0_, ue1_, ue2_, ue3_, pe_);                                  \
        STOREU(uo0_, uo1_, uo2_, uo3_, pe_ + 1);                              \
    }

#define WAITV(N)                                                              \
    asm volatile("s_waitcnt vmcnt(" #N ")" ::: "memory");                     \
    __builtin_amdgcn_sched_barrier(0);

    LOADP(0, 0);
    LOADP(1, 1);
    // it0: Q=[L0 8, L1 8] -> wait(8) retires L0
    WAITV(8);  COMPUTEP(0, 0); LOADP(2, 0);
    // it1: Q=[L1 8, st0 4, L2 8] -> wait(12) retires L1
    WAITV(12); COMPUTEP(1, 1); LOADP(3, 1);
    // it2: Q=[st0 4, L2 8, st1 4, L3 8] -> wait(12) retires st0+L2
    WAITV(12); COMPUTEP(2, 0);
    // it3: Q=[st1 4, L3 8, st2 4] -> wait(4) retires st1+L3
    WAITV(4);  COMPUTEP(3, 1);

    // iter-0 partial s0: sp0[l][ch*4+w][b=cc][sv], 4x float4 contiguous
    {
        float* sb = sp0 + (((size_t)l * 128 + ch * 4 + w) * 16 + cc) * 64 + kb * 16;
        float4 q0 = {cacc0[0], cacc1[0], cacc2[0], cacc3[0]};
        float4 q1 = {cacc0[1], cacc1[1], cacc2[1], cacc3[1]};
        float4 q2 = {cacc0[2], cacc1[2], cacc2[2], cacc3[2]};
        float4 q3 = {cacc0[3], cacc1[3], cacc2[3], cacc3[3]};
        *reinterpret_cast<float4*>(sb + 0) = q0;
        *reinterpret_cast<float4*>(sb + 4) = q1;
        *reinterpret_cast<float4*>(sb + 8) = q2;
        *reinterpret_cast<float4*>(sb + 12) = q3;
    }
#undef LOADP
#undef ONEG
#undef STOREU
#undef COMPUTEP
#undef WAITV
}

// ---------------------------------------------------------------------------
// K_v: generic chunk-reduce + squash (sv space). unperm=1 -> write true-v.
// ---------------------------------------------------------------------------
__global__ __launch_bounds__(256) void k_v(const float* __restrict__ sp,
                                           size_t cb, size_t cl, size_t cs,
                                           int nch, float scale, int unperm,
                                           float* __restrict__ vout,
                                           float* __restrict__ norms) {
    const int b = blockIdx.y;
    const int w = threadIdx.x >> 6, lane = threadIdx.x & 63;
    const int l = blockIdx.x * 4 + w;
    const float* p = sp + cb * b + cl * l + lane;
    float s = 0.f;
#pragma unroll 8
    for (int ch = 0; ch < nch; ++ch) s += p[(size_t)ch * cs];
    s *= scale;
    float sq = wsum64(s * s);
    float f = sqrtf(sq) / (1.0f + sq);
    const int vi = unperm ? ((lane & 3) * 16 + (lane >> 4) * 4 + ((lane >> 2) & 3))
                          : lane;
    vout[((size_t)b * L + l) * V + vi] = s * f;
    if (norms && lane == 0) norms[b * L + l] = sq / (1.0f + sq);
}

// ---------------------------------------------------------------------------
// K_bc: block = (ch of 16 p, b), 512 threads. u tile in REGISTERS.
// uhat layout [l][p][b][sv]; all v-space math in sv space (invariant).
// ---------------------------------------------------------------------------
__global__ __launch_bounds__(512, 4) void k_bc(const ushort* __restrict__ uhat,
                                               const float* __restrict__ vv,
                                               float* __restrict__ bbuf,
                                               float* __restrict__ sp,
                                               float* __restrict__ Tsum,
                                               int add_prev, int do_T) {
    const int ch = blockIdx.x, b = blockIdx.y;
    const int p0 = ch * CHBC;
    const int t = threadIdx.x;
    const int w = t >> 6, lane = t & 63;
    const int pl8 = lane >> 3;
    const int vg8 = lane & 7;
    const int l0 = w * 8;

    __shared__ float vsh[L][V];
    __shared__ float bl[CHBC][L + 1];
    __shared__ float twv[8];

    {
        const float4* vvp = reinterpret_cast<const float4*>(vv + (size_t)b * L * V);
        float4* vshp = reinterpret_cast<float4*>(&vsh[0][0]);
#pragma unroll
        for (int i = 0; i < 2; ++i) vshp[t + i * 512] = vvp[t + i * 512];
    }

    const size_t LSTR = (size_t)P * B * V;   // l stride
    ushort8_t ur[8][2];
    {
        const ushort* ubase = uhat + (((size_t)l0 * P + p0 + pl8) * B + b) * V + vg8 * 8;
#pragma unroll
        for (int li = 0; li < 8; ++li) {
#pragma unroll
            for (int ph = 0; ph < 2; ++ph)
                ur[li][ph] = *reinterpret_cast<const ushort8_t*>(
                    ubase + (size_t)li * LSTR + (size_t)ph * 8 * B * V);
        }
    }
    __syncthreads();

#pragma unroll
    for (int li = 0; li < 8; ++li) {
        const int l = l0 + li;
        const float4 va = *reinterpret_cast<const float4*>(&vsh[l][vg8 * 8]);
        const float4 vb = *reinterpret_cast<const float4*>(&vsh[l][vg8 * 8 + 4]);
#pragma unroll
        for (int ph = 0; ph < 2; ++ph) {
            float d;
            d = bf2f(ur[li][ph][0]) * va.x;
            d = fmaf(bf2f(ur[li][ph][1]), va.y, d);
            d = fmaf(bf2f(ur[li][ph][2]), va.z, d);
            d = fmaf(bf2f(ur[li][ph][3]), va.w, d);
            d = fmaf(bf2f(ur[li][ph][4]), vb.x, d);
            d = fmaf(bf2f(ur[li][ph][5]), vb.y, d);
            d = fmaf(bf2f(ur[li][ph][6]), vb.z, d);
            d = fmaf(bf2f(ur[li][ph][7]), vb.w, d);
            d += __shfl_xor(d, 1, 64);
            d += __shfl_xor(d, 2, 64);
            d += __shfl_xor(d, 4, 64);
            if (vg8 == 0) bl[ph * 8 + pl8][l] = d;
        }
    }
    __syncthreads();

    float tloc = 0.f;
#pragma unroll
    for (int pi = 0; pi < 2; ++pi) {
        const int pli = w * 2 + pi;
        const int p = p0 + pli;
        float bv = bl[pli][lane];
        float* bp = bbuf + ((size_t)b * P + p) * L;
        if (add_prev) bv += bp[lane];
        bp[lane] = bv;
        float m = wmax64(bv);
        float e = __expf(bv - m);
        float ssum = wsum64(e);
        float cc = e / ssum;
        bl[pli][lane] = cc;
        if (do_T) tloc += cc * __logf(64.0f * (cc + 1e-12f));
    }
    if (do_T) {
        float dsum = wsum64(tloc);
        if (lane == 0) twv[w] = dsum;
    }
    __syncthreads();
    if (do_T && t == 0) {
        float s8 = twv[0] + twv[1] + twv[2] + twv[3] +
                   twv[4] + twv[5] + twv[6] + twv[7];
        atomicAdd(Tsum, s8 * (1.0f / LN64));
    }

    float* spb = sp + (size_t)(b * NCH_BC + ch) * L * V;
#pragma unroll
    for (int li = 0; li < 8; ++li) {
        const int l = l0 + li;
        const float cA = bl[pl8][l];
        const float cB = bl[8 + pl8][l];
        float4 pa, pb;
        pa.x = cA * bf2f(ur[li][0][0]) + cB * bf2f(ur[li][1][0]);
        pa.y = cA * bf2f(ur[li][0][1]) + cB * bf2f(ur[li][1][1]);
        pa.z = cA * bf2f(ur[li][0][2]) + cB * bf2f(ur[li][1][2]);
        pa.w = cA * bf2f(ur[li][0][3]) + cB * bf2f(ur[li][1][3]);
        pb.x = cA * bf2f(ur[li][0][4]) + cB * bf2f(ur[li][1][4]);
        pb.y = cA * bf2f(ur[li][0][5]) + cB * bf2f(ur[li][1][5]);
        pb.z = cA * bf2f(ur[li][0][6]) + cB * bf2f(ur[li][1][6]);
        pb.w = cA * bf2f(ur[li][0][7]) + cB * bf2f(ur[li][1][7]);
#pragma unroll
        for (int m = 8; m <= 32; m <<= 1) {
            pa.x += __shfl_xor(pa.x, m, 64);
            pa.y += __shfl_xor(pa.y, m, 64);
            pa.z += __shfl_xor(pa.z, m, 64);
            pa.w += __shfl_xor(pa.w, m, 64);
            pb.x += __shfl_xor(pb.x, m, 64);
            pb.y += __shfl_xor(pb.y, m, 64);
            pb.z += __shfl_xor(pb.z, m, 64);
            pb.w += __shfl_xor(pb.w, m, 64);
        }
        if (pl8 == 0) {
            *reinterpret_cast<float4*>(spb + (size_t)l * V + vg8 * 8) = pa;
            *reinterpret_cast<float4*>(spb + (size_t)l * V + vg8 * 8 + 4) = pb;
        }
    }
}

// ---------------------------------------------------------------------------
// K_final: T and D. One block, 64 threads (lane = l).
// ---------------------------------------------------------------------------
__global__ void k_final(const float* __restrict__ Tsum,
                        const float* __restrict__ norms,
                        float* __restrict__ out) {
    const int lane = threadIdx.x & 63;
    float n[B];
    float sum = 0.f;
#pragma unroll
    for (int b = 0; b < B; ++b) { n[b] = norms[b * L + lane]; sum += n[b]; }
    const float mean = sum * (1.0f / B);
    float var = 0.f;
#pragma unroll
    for (int b = 0; b < B; ++b) { float d = n[b] - mean; var = fmaf(d, d, var); }
    var *= (1.0f / B);
    float sd = sqrtf(var);
    float D = wmax64(sd);
    if (lane == 0) {
        out[B * L * V] = Tsum[0] * (1.0f / (B * P));
        out[B * L * V + 1] = D;
    }
}

extern "C" void kernel_launch(void* const* d_in, const int* in_sizes, int n_in,
                              void* d_out, int out_size, void* d_ws, size_t ws_size,
                              hipStream_t stream) {
    const float* x = (const float*)d_in[0];   // (B,P,Q)
    const float* W = (const float*)d_in[1];   // (L,P,V,Q)
    float* out = (float*)d_out;               // v (B,L,V) then T, D

    char* ws = (char*)d_ws;
    ushort* uhat = (ushort*)ws;                        // [l][p][b][sv] bf16 = 128 MB
    size_t off = (size_t)B * L * P * V * 2;
    float* spbuf = (float*)(ws + off);                 // 32 MB region:
    // sp0 [l][128][16][64] (32 MB, iter-0) overlaps sp [b][64][l][v] (16 MB)
    off += (size_t)64 * 128 * 16 * 64 * 4;
    float* vbuf  = (float*)(ws + off); off += (size_t)B * L * V * 4;
    float* bbuf  = (float*)(ws + off); off += (size_t)B * P * L * 4;   // 4 MB
    float* norms = (float*)(ws + off); off += (size_t)B * L * 4;
    float* Tsum  = (float*)(ws + off); off += 256;

    hipMemsetAsync(Tsum, 0, sizeof(float), stream);

    // u_hat: reg-direct coalesced loads + MFMA + fused s0
    hipLaunchKernelGGL(k_uhat, dim3(32, 64), dim3(256), 0, stream, W, x, uhat, spbuf);
    // v0 = squash((1/64) * reduce sp0)   (sv space)
    hipLaunchKernelGGL(k_v, dim3(L / 4, B), dim3(256), 0, stream,
                       spbuf, (size_t)64, (size_t)131072, (size_t)1024, 128,
                       1.0f / 64.0f, 0, vbuf, (float*)nullptr);
    // b1 = v0.u ; c1 ; partial s1 -> sp[b][ch][l][sv]
    hipLaunchKernelGGL(k_bc, dim3(NCH_BC, B), dim3(512), 0, stream,
                       uhat, vbuf, bbuf, spbuf, Tsum, 0, 0);
    // v1 (sv space)
    hipLaunchKernelGGL(k_v, dim3(L / 4, B), dim3(256), 0, stream,
                       spbuf, (size_t)NCH_BC * L * V, (size_t)V, (size_t)L * V,
                       NCH_BC, 1.0f, 0, vbuf, (float*)nullptr);
    // b2 = b1 + v1.u ; c2 ; T partials ; partial s2
    hipLaunchKernelGGL(k_bc, dim3(NCH_BC, B), dim3(512), 0, stream,
                       uhat, vbuf, bbuf, spbuf, Tsum, 1, 1);
    // v2 -> out (un-permuted to true v), norms
    hipLaunchKernelGGL(k_v, dim3(L / 4, B), dim3(256), 0, stream,
                       spbuf, (size_t)NCH_BC * L * V, (size_t)V, (size_t)L * V,
                       NCH_BC, 1.0f, 1, out, norms);
    hipLaunchKernelGGL(k_final, dim3(1), dim3(64), 0, stream, Tsum, norms, out);
}

// Round 21
// 211.401 us; speedup vs baseline: 1.0677x; 1.0520x over previous
//
#include <hip/hip_runtime.h>
#include <hip/hip_bf16.h>

#define B 16
#define L 64
#define P 1024
#define V 64
#define Q 16
#define LN64 4.158883083359672f

#define CHBC 16           // p per k_bc block
#define NCH_BC (P / CHBC) // 64

typedef unsigned short ushort8_t __attribute__((ext_vector_type(8)));
typedef __attribute__((ext_vector_type(8))) short bf16x8;
typedef __attribute__((ext_vector_type(4))) float f32x4;

static __device__ __forceinline__ float bf2f(ushort u) {
    return __uint_as_float(((unsigned int)u) << 16);
}
static __device__ __forceinline__ ushort f2bf(float f) {
    unsigned int x = __float_as_uint(f);
    unsigned int r = (x + 0x7fffu + ((x >> 16) & 1u)) >> 16;
    return (ushort)r;
}
static __device__ __forceinline__ unsigned pk2(float lo, float hi) {
    return (unsigned)f2bf(lo) | ((unsigned)f2bf(hi) << 16);
}

static __device__ __forceinline__ float wsum64(float v) {
#pragma unroll
    for (int m = 32; m > 0; m >>= 1) v += __shfl_xor(v, m, 64);
    return v;
}
static __device__ __forceinline__ float wmax64(float v) {
#pragma unroll
    for (int m = 32; m > 0; m >>= 1) v = fmaxf(v, __shfl_xor(v, m, 64));
    return v;
}

union FragU { uint4 u; bf16x8 s; };

// ---------------------------------------------------------------------------
// K_uhat v21: v20's reg-direct coalesced MFMA, COMPILER-SCHEDULED (zero
// inline asm, zero sched_barrier). Rationale: every producer since round 9
// pinned instruction order with hand waits; the only 5.8 TB/s kernel here
// (k_bc) is pure C++ -- the compiler issues all loads up front and inserts
// minimal waitcnts (guide Common-mistake #5: source-level pipelining fights
// the scheduler). Per wave: 2 p-pairs (4 p), 16 float4 W loads as plain
// reads -> wl regs (64 VGPR), 16 MFMAs, sv-layout uint4 stores. Grid
// (P/16=64, L=64) = 4096 blocks. s0 partials block-reduced via LDS ->
// sp0[l][ch][b][sv] (64 chunks, 16.7 MB). ~130 VGPR @ (256,3).
// ---------------------------------------------------------------------------
__global__ __launch_bounds__(256, 3) void k_uhat(const float* __restrict__ Wt,
                                                 const float* __restrict__ x,
                                                 ushort* __restrict__ uhat,
                                                 float* __restrict__ sp0) {
    const int t = threadIdx.x;
    const int w = t >> 6;
    const int lane = t & 63;
    const int kb = lane >> 4;     // k-octet (0..3); kb>=2 -> p_odd role
    const int cc = lane & 15;     // A row (v low) / D col (b)
    const int ch = blockIdx.x;    // p-chunk of 16
    const int l = blockIdx.y;
    const int p0 = ch * 16;

    __shared__ unsigned int xstage[16][32][4];   // 8 KB packed-bf16 x
    __shared__ float wred[4][16][64];            // 16 KB s0 wave partials

#pragma unroll
    for (int i = 0; i < 8; ++i) {
        const int e = i * 256 + t;        // 2048 entries
        const int pp = e >> 7, ln = (e >> 2) & 31, m = e & 3;
        const int b = ln & 15, qb = (ln >> 4) * 8;
        const float2 xv = *reinterpret_cast<const float2*>(
            x + ((size_t)b * P + p0 + pp) * Q + qb + 2 * m);
        xstage[pp][ln][m] = pk2(xv.x, xv.y);
    }
    __syncthreads();

    // B-frag variants per pair: afe (x in k<16), afo (x in k>=16)
    uint4 afe[2], afo[2];
#pragma unroll
    for (int i = 0; i < 2; ++i) {
        if (lane < 32)
            afe[i] = *reinterpret_cast<const uint4*>(&xstage[w * 4 + 2 * i][lane][0]);
        else
            afe[i] = (uint4){0u, 0u, 0u, 0u};
        if (lane >= 32)
            afo[i] = *reinterpret_cast<const uint4*>(&xstage[w * 4 + 2 * i + 1][lane - 32][0]);
        else
            afo[i] = (uint4){0u, 0u, 0u, 0u};
    }

    const float* gW = Wt + ((size_t)l * P + p0 + w * 4) * (V * Q);
    // per-lane base within pair: p_loc = 2i + (kb>>1); row v = g*16+cc; q-octet kb&1
    const float* lb = gW + (size_t)(kb >> 1) * (V * Q) + cc * Q + (kb & 1) * 8;

    f32x4 cacc0 = {0.f, 0.f, 0.f, 0.f}, cacc1 = {0.f, 0.f, 0.f, 0.f};
    f32x4 cacc2 = {0.f, 0.f, 0.f, 0.f}, cacc3 = {0.f, 0.f, 0.f, 0.f};
    float4 wl[2][8];

    // issue ALL W loads as plain reads -- compiler schedules/waits (k_bc style)
#pragma unroll
    for (int i = 0; i < 2; ++i) {
        const float* bp = lb + (size_t)(2 * i) * (V * Q);
#pragma unroll
        for (int g = 0; g < 4; ++g) {
            wl[i][2 * g + 0] = *(const float4*)(bp + g * 256);
            wl[i][2 * g + 1] = *(const float4*)(bp + g * 256 + 4);
        }
    }

#define ONEG(g_, i_, cacc_, ue_, uo_)                                         \
    {                                                                         \
        FragU wf_;                                                            \
        const float4 f0_ = wl[i_][2 * g_ + 0];                                \
        const float4 f1_ = wl[i_][2 * g_ + 1];                                \
        wf_.u = (uint4){pk2(f0_.x, f0_.y), pk2(f0_.z, f0_.w),                 \
                        pk2(f1_.x, f1_.y), pk2(f1_.z, f1_.w)};                \
        f32x4 De_ = __builtin_amdgcn_mfma_f32_16x16x32_bf16(wf_.s, axe_.s,    \
                                                            cacc_, 0, 0, 0);  \
        ue_ = De_ - cacc_;                                                    \
        f32x4 Do_ = __builtin_amdgcn_mfma_f32_16x16x32_bf16(wf_.s, axo_.s,    \
                                                            De_, 0, 0, 0);    \
        uo_ = Do_ - De_;                                                      \
        cacc_ = Do_;                                                          \
    }

#define STOREU(u0_, u1_, u2_, u3_, p_)                                        \
    {                                                                         \
        uint4 A_, Bv_;                                                        \
        A_.x = pk2(u0_[0], u1_[0]); A_.y = pk2(u2_[0], u3_[0]);               \
        A_.z = pk2(u0_[1], u1_[1]); A_.w = pk2(u2_[1], u3_[1]);               \
        Bv_.x = pk2(u0_[2], u1_[2]); Bv_.y = pk2(u2_[2], u3_[2]);             \
        Bv_.z = pk2(u0_[3], u1_[3]); Bv_.w = pk2(u2_[3], u3_[3]);             \
        ushort* ub_ = uhat + (((size_t)l * P + (p_)) * B + cc) * V + kb * 16; \
        *reinterpret_cast<uint4*>(ub_) = A_;                                  \
        *reinterpret_cast<uint4*>(ub_ + 8) = Bv_;                             \
    }

#pragma unroll
    for (int i = 0; i < 2; ++i) {
        FragU axe_; axe_.u = afe[i];
        FragU axo_; axo_.u = afo[i];
        f32x4 ue0, ue1, ue2, ue3, uo0, uo1, uo2, uo3;
        ONEG(0, i, cacc0, ue0, uo0);
        ONEG(1, i, cacc1, ue1, uo1);
        ONEG(2, i, cacc2, ue2, uo2);
        ONEG(3, i, cacc3, ue3, uo3);
        const int pe = p0 + w * 4 + 2 * i;
        STOREU(ue0, ue1, ue2, ue3, pe);
        STOREU(uo0, uo1, uo2, uo3, pe + 1);
    }
#undef ONEG
#undef STOREU

    // s0: wave partials -> LDS, block-reduce over waves -> sp0[l][ch][b][sv]
    {
        float* wb = &wred[w][cc][kb * 16];
        float4 q0 = {cacc0[0], cacc1[0], cacc2[0], cacc3[0]};
        float4 q1 = {cacc0[1], cacc1[1], cacc2[1], cacc3[1]};
        float4 q2 = {cacc0[2], cacc1[2], cacc2[2], cacc3[2]};
        float4 q3 = {cacc0[3], cacc1[3], cacc2[3], cacc3[3]};
        *reinterpret_cast<float4*>(wb + 0) = q0;
        *reinterpret_cast<float4*>(wb + 4) = q1;
        *reinterpret_cast<float4*>(wb + 8) = q2;
        *reinterpret_cast<float4*>(wb + 12) = q3;
    }
    __syncthreads();
    {
        const int o = t * 4;           // output quad: b = o>>6, sv = o&63
        const int b = o >> 6, sv = o & 63;
        const float* r0 = &wred[0][b][sv];
        const float* r1 = &wred[1][b][sv];
        const float* r2 = &wred[2][b][sv];
        const float* r3 = &wred[3][b][sv];
        float4 s;
        s.x = r0[0] + r1[0] + r2[0] + r3[0];
        s.y = r0[1] + r1[1] + r2[1] + r3[1];
        s.z = r0[2] + r1[2] + r2[2] + r3[2];
        s.w = r0[3] + r1[3] + r2[3] + r3[3];
        *reinterpret_cast<float4*>(
            sp0 + (((size_t)l * 64 + ch) * 16 + b) * 64 + sv) = s;
    }
}

// ---------------------------------------------------------------------------
// K_v: generic chunk-reduce + squash (sv space). unperm=1 -> write true-v.
// ---------------------------------------------------------------------------
__global__ __launch_bounds__(256) void k_v(const float* __restrict__ sp,
                                           size_t cb, size_t cl, size_t cs,
                                           int nch, float scale, int unperm,
                                           float* __restrict__ vout,
                                           float* __restrict__ norms) {
    const int b = blockIdx.y;
    const int w = threadIdx.x >> 6, lane = threadIdx.x & 63;
    const int l = blockIdx.x * 4 + w;
    const float* p = sp + cb * b + cl * l + lane;
    float s = 0.f;
#pragma unroll 8
    for (int ch = 0; ch < nch; ++ch) s += p[(size_t)ch * cs];
    s *= scale;
    float sq = wsum64(s * s);
    float f = sqrtf(sq) / (1.0f + sq);
    const int vi = unperm ? ((lane & 3) * 16 + (lane >> 4) * 4 + ((lane >> 2) & 3))
                          : lane;
    vout[((size_t)b * L + l) * V + vi] = s * f;
    if (norms && lane == 0) norms[b * L + l] = sq / (1.0f + sq);
}

// ---------------------------------------------------------------------------
// K_bc: block = (ch of 16 p, b), 512 threads. u tile in REGISTERS.
// uhat layout [l][p][b][sv]; all v-space math in sv space (invariant).
// ---------------------------------------------------------------------------
__global__ __launch_bounds__(512, 4) void k_bc(const ushort* __restrict__ uhat,
                                               const float* __restrict__ vv,
                                               float* __restrict__ bbuf,
                                               float* __restrict__ sp,
                                               float* __restrict__ Tsum,
                                               int add_prev, int do_T) {
    const int ch = blockIdx.x, b = blockIdx.y;
    const int p0 = ch * CHBC;
    const int t = threadIdx.x;
    const int w = t >> 6, lane = t & 63;
    const int pl8 = lane >> 3;
    const int vg8 = lane & 7;
    const int l0 = w * 8;

    __shared__ float vsh[L][V];
    __shared__ float bl[CHBC][L + 1];
    __shared__ float twv[8];

    {
        const float4* vvp = reinterpret_cast<const float4*>(vv + (size_t)b * L * V);
        float4* vshp = reinterpret_cast<float4*>(&vsh[0][0]);
#pragma unroll
        for (int i = 0; i < 2; ++i) vshp[t + i * 512] = vvp[t + i * 512];
    }

    const size_t LSTR = (size_t)P * B * V;   // l stride
    ushort8_t ur[8][2];
    {
        const ushort* ubase = uhat + (((size_t)l0 * P + p0 + pl8) * B + b) * V + vg8 * 8;
#pragma unroll
        for (int li = 0; li < 8; ++li) {
#pragma unroll
            for (int ph = 0; ph < 2; ++ph)
                ur[li][ph] = *reinterpret_cast<const ushort8_t*>(
                    ubase + (size_t)li * LSTR + (size_t)ph * 8 * B * V);
        }
    }
    __syncthreads();

#pragma unroll
    for (int li = 0; li < 8; ++li) {
        const int l = l0 + li;
        const float4 va = *reinterpret_cast<const float4*>(&vsh[l][vg8 * 8]);
        const float4 vb = *reinterpret_cast<const float4*>(&vsh[l][vg8 * 8 + 4]);
#pragma unroll
        for (int ph = 0; ph < 2; ++ph) {
            float d;
            d = bf2f(ur[li][ph][0]) * va.x;
            d = fmaf(bf2f(ur[li][ph][1]), va.y, d);
            d = fmaf(bf2f(ur[li][ph][2]), va.z, d);
            d = fmaf(bf2f(ur[li][ph][3]), va.w, d);
            d = fmaf(bf2f(ur[li][ph][4]), vb.x, d);
            d = fmaf(bf2f(ur[li][ph][5]), vb.y, d);
            d = fmaf(bf2f(ur[li][ph][6]), vb.z, d);
            d = fmaf(bf2f(ur[li][ph][7]), vb.w, d);
            d += __shfl_xor(d, 1, 64);
            d += __shfl_xor(d, 2, 64);
            d += __shfl_xor(d, 4, 64);
            if (vg8 == 0) bl[ph * 8 + pl8][l] = d;
        }
    }
    __syncthreads();

    float tloc = 0.f;
#pragma unroll
    for (int pi = 0; pi < 2; ++pi) {
        const int pli = w * 2 + pi;
        const int p = p0 + pli;
        float bv = bl[pli][lane];
        float* bp = bbuf + ((size_t)b * P + p) * L;
        if (add_prev) bv += bp[lane];
        bp[lane] = bv;
        float m = wmax64(bv);
        float e = __expf(bv - m);
        float ssum = wsum64(e);
        float cc = e / ssum;
        bl[pli][lane] = cc;
        if (do_T) tloc += cc * __logf(64.0f * (cc + 1e-12f));
    }
    if (do_T) {
        float dsum = wsum64(tloc);
        if (lane == 0) twv[w] = dsum;
    }
    __syncthreads();
    if (do_T && t == 0) {
        float s8 = twv[0] + twv[1] + twv[2] + twv[3] +
                   twv[4] + twv[5] + twv[6] + twv[7];
        atomicAdd(Tsum, s8 * (1.0f / LN64));
    }

    float* spb = sp + (size_t)(b * NCH_BC + ch) * L * V;
#pragma unroll
    for (int li = 0; li < 8; ++li) {
        const int l = l0 + li;
        const float cA = bl[pl8][l];
        const float cB = bl[8 + pl8][l];
        float4 pa, pb;
        pa.x = cA * bf2f(ur[li][0][0]) + cB * bf2f(ur[li][1][0]);
        pa.y = cA * bf2f(ur[li][0][1]) + cB * bf2f(ur[li][1][1]);
        pa.z = cA * bf2f(ur[li][0][2]) + cB * bf2f(ur[li][1][2]);
        pa.w = cA * bf2f(ur[li][0][3]) + cB * bf2f(ur[li][1][3]);
        pb.x = cA * bf2f(ur[li][0][4]) + cB * bf2f(ur[li][1][4]);
        pb.y = cA * bf2f(ur[li][0][5]) + cB * bf2f(ur[li][1][5]);
        pb.z = cA * bf2f(ur[li][0][6]) + cB * bf2f(ur[li][1][6]);
        pb.w = cA * bf2f(ur[li][0][7]) + cB * bf2f(ur[li][1][7]);
#pragma unroll
        for (int m = 8; m <= 32; m <<= 1) {
            pa.x += __shfl_xor(pa.x, m, 64);
            pa.y += __shfl_xor(pa.y, m, 64);
            pa.z += __shfl_xor(pa.z, m, 64);
            pa.w += __shfl_xor(pa.w, m, 64);
            pb.x += __shfl_xor(pb.x, m, 64);
            pb.y += __shfl_xor(pb.y, m, 64);
            pb.z += __shfl_xor(pb.z, m, 64);
            pb.w += __shfl_xor(pb.w, m, 64);
        }
        if (pl8 == 0) {
            *reinterpret_cast<float4*>(spb + (size_t)l * V + vg8 * 8) = pa;
            *reinterpret_cast<float4*>(spb + (size_t)l * V + vg8 * 8 + 4) = pb;
        }
    }
}

// ---------------------------------------------------------------------------
// K_final: T and D. One block, 64 threads (lane = l).
// ---------------------------------------------------------------------------
__global__ void k_final(const float* __restrict__ Tsum,
                        const float* __restrict__ norms,
                        float* __restrict__ out) {
    const int lane = threadIdx.x & 63;
    float n[B];
    float sum = 0.f;
#pragma unroll
    for (int b = 0; b < B; ++b) { n[b] = norms[b * L + lane]; sum += n[b]; }
    const float mean = sum * (1.0f / B);
    float var = 0.f;
#pragma unroll
    for (int b = 0; b < B; ++b) { float d = n[b] - mean; var = fmaf(d, d, var); }
    var *= (1.0f / B);
    float sd = sqrtf(var);
    float D = wmax64(sd);
    if (lane == 0) {
        out[B * L * V] = Tsum[0] * (1.0f / (B * P));
        out[B * L * V + 1] = D;
    }
}

extern "C" void kernel_launch(void* const* d_in, const int* in_sizes, int n_in,
                              void* d_out, int out_size, void* d_ws, size_t ws_size,
                              hipStream_t stream) {
    const float* x = (const float*)d_in[0];   // (B,P,Q)
    const float* W = (const float*)d_in[1];   // (L,P,V,Q)
    float* out = (float*)d_out;               // v (B,L,V) then T, D

    char* ws = (char*)d_ws;
    ushort* uhat = (ushort*)ws;                        // [l][p][b][sv] bf16 = 128 MB
    size_t off = (size_t)B * L * P * V * 2;
    float* spbuf = (float*)(ws + off);                 // 32 MB region:
    // sp0 [l][64][16][64] (16.7 MB) and sp [b][64][l][sv] (16.7 MB) share it
    off += (size_t)64 * 128 * 16 * 64 * 4;
    float* vbuf  = (float*)(ws + off); off += (size_t)B * L * V * 4;
    float* bbuf  = (float*)(ws + off); off += (size_t)B * P * L * 4;   // 4 MB
    float* norms = (float*)(ws + off); off += (size_t)B * L * 4;
    float* Tsum  = (float*)(ws + off); off += 256;

    hipMemsetAsync(Tsum, 0, sizeof(float), stream);

    // u_hat: compiler-scheduled reg-direct MFMA + fused s0 (block-reduced)
    hipLaunchKernelGGL(k_uhat, dim3(64, 64), dim3(256), 0, stream, W, x, uhat, spbuf);
    // v0 = squash((1/64) * reduce sp0)   sp0 idx = l*65536 + ch*1024 + b*64 + sv
    hipLaunchKernelGGL(k_v, dim3(L / 4, B), dim3(256), 0, stream,
                       spbuf, (size_t)64, (size_t)65536, (size_t)1024, 64,
                       1.0f / 64.0f, 0, vbuf, (float*)nullptr);
    // b1 = v0.u ; c1 ; partial s1 -> sp[b][ch][l][sv]
    hipLaunchKernelGGL(k_bc, dim3(NCH_BC, B), dim3(512), 0, stream,
                       uhat, vbuf, bbuf, spbuf, Tsum, 0, 0);
    // v1 (sv space)
    hipLaunchKernelGGL(k_v, dim3(L / 4, B), dim3(256), 0, stream,
                       spbuf, (size_t)NCH_BC * L * V, (size_t)V, (size_t)L * V,
                       NCH_BC, 1.0f, 0, vbuf, (float*)nullptr);
    // b2 = b1 + v1.u ; c2 ; T partials ; partial s2
    hipLaunchKernelGGL(k_bc, dim3(NCH_BC, B), dim3(512), 0, stream,
                       uhat, vbuf, bbuf, spbuf, Tsum, 1, 1);
    // v2 -> out (un-permuted to true v), norms
    hipLaunchKernelGGL(k_v, dim3(L / 4, B), dim3(256), 0, stream,
                       spbuf, (size_t)NCH_BC * L * V, (size_t)V, (size_t)L * V,
                       NCH_BC, 1.0f, 1, out, norms);
    hipLaunchKernelGGL(k_final, dim3(1), dim3(64), 0, stream, Tsum, norms, out);
}

// Round 22
// 204.851 us; speedup vs baseline: 1.1018x; 1.0320x over previous
//
#include <hip/hip_runtime.h>
#include <hip/hip_bf16.h>

#define B 16
#define L 64
#define P 1024
#define V 64
#define Q 16
#define LN64 4.158883083359672f

#define CHBC 16           // p per k_bc block
#define NCH_BC (P / CHBC) // 64

typedef unsigned short ushort8_t __attribute__((ext_vector_type(8)));
typedef __attribute__((ext_vector_type(8))) short bf16x8;
typedef __attribute__((ext_vector_type(4))) float f32x4;

static __device__ __forceinline__ float bf2f(ushort u) {
    return __uint_as_float(((unsigned int)u) << 16);
}
static __device__ __forceinline__ ushort f2bf(float f) {
    unsigned int x = __float_as_uint(f);
    unsigned int r = (x + 0x7fffu + ((x >> 16) & 1u)) >> 16;
    return (ushort)r;
}
static __device__ __forceinline__ unsigned pk2(float lo, float hi) {
    return (unsigned)f2bf(lo) | ((unsigned)f2bf(hi) << 16);
}

static __device__ __forceinline__ float wsum64(float v) {
#pragma unroll
    for (int m = 32; m > 0; m >>= 1) v += __shfl_xor(v, m, 64);
    return v;
}
static __device__ __forceinline__ float wmax64(float v) {
#pragma unroll
    for (int m = 32; m > 0; m >>= 1) v = fmaxf(v, __shfl_xor(v, m, 64));
    return v;
}

union FragU { uint4 u; bf16x8 s; };

// ---------------------------------------------------------------------------
// K_uhat v22: v21 (compiler-scheduled reg-direct MFMA -- the one producer
// change that ever helped, 222->211) with VGPR dieted under the 128 cliff:
//  - afe/afo preload arrays removed (-16 VGPR): each pair's x-frags are read
//    from the persistent xstage LDS at use (no rings -> no aliasing);
//  - __launch_bounds__(256, 4): cap 128. m69: waves/CU steps 12->16 at
//    vgpr<=128. k_bc (5.8 TB/s) runs 16 waves/CU; v21 ran 12 at ~130 VGPR.
// Single-variable occupancy test; everything else identical to v21.
// ---------------------------------------------------------------------------
__global__ __launch_bounds__(256, 4) void k_uhat(const float* __restrict__ Wt,
                                                 const float* __restrict__ x,
                                                 ushort* __restrict__ uhat,
                                                 float* __restrict__ sp0) {
    const int t = threadIdx.x;
    const int w = t >> 6;
    const int lane = t & 63;
    const int kb = lane >> 4;     // k-octet (0..3); kb>=2 -> p_odd role
    const int cc = lane & 15;     // A row (v low) / D col (b)
    const int ch = blockIdx.x;    // p-chunk of 16
    const int l = blockIdx.y;
    const int p0 = ch * 16;

    __shared__ unsigned int xstage[16][32][4];   // 8 KB packed-bf16 x
    __shared__ float wred[4][16][64];            // 16 KB s0 wave partials

#pragma unroll
    for (int i = 0; i < 8; ++i) {
        const int e = i * 256 + t;        // 2048 entries
        const int pp = e >> 7, ln = (e >> 2) & 31, m = e & 3;
        const int b = ln & 15, qb = (ln >> 4) * 8;
        const float2 xv = *reinterpret_cast<const float2*>(
            x + ((size_t)b * P + p0 + pp) * Q + qb + 2 * m);
        xstage[pp][ln][m] = pk2(xv.x, xv.y);
    }
    __syncthreads();

    const float* gW = Wt + ((size_t)l * P + p0 + w * 4) * (V * Q);
    // per-lane base within pair: p_loc = 2i + (kb>>1); row v = g*16+cc; q-octet kb&1
    const float* lb = gW + (size_t)(kb >> 1) * (V * Q) + cc * Q + (kb & 1) * 8;

    f32x4 cacc0 = {0.f, 0.f, 0.f, 0.f}, cacc1 = {0.f, 0.f, 0.f, 0.f};
    f32x4 cacc2 = {0.f, 0.f, 0.f, 0.f}, cacc3 = {0.f, 0.f, 0.f, 0.f};
    float4 wl[2][8];

    // issue ALL W loads as plain reads -- compiler schedules/waits (k_bc style)
#pragma unroll
    for (int i = 0; i < 2; ++i) {
        const float* bp = lb + (size_t)(2 * i) * (V * Q);
#pragma unroll
        for (int g = 0; g < 4; ++g) {
            wl[i][2 * g + 0] = *(const float4*)(bp + g * 256);
            wl[i][2 * g + 1] = *(const float4*)(bp + g * 256 + 4);
        }
    }

#define ONEG(g_, i_, cacc_, ue_, uo_)                                         \
    {                                                                         \
        FragU wf_;                                                            \
        const float4 f0_ = wl[i_][2 * g_ + 0];                                \
        const float4 f1_ = wl[i_][2 * g_ + 1];                                \
        wf_.u = (uint4){pk2(f0_.x, f0_.y), pk2(f0_.z, f0_.w),                 \
                        pk2(f1_.x, f1_.y), pk2(f1_.z, f1_.w)};                \
        f32x4 De_ = __builtin_amdgcn_mfma_f32_16x16x32_bf16(wf_.s, axe_.s,    \
                                                            cacc_, 0, 0, 0);  \
        ue_ = De_ - cacc_;                                                    \
        f32x4 Do_ = __builtin_amdgcn_mfma_f32_16x16x32_bf16(wf_.s, axo_.s,    \
                                                            De_, 0, 0, 0);    \
        uo_ = Do_ - De_;                                                      \
        cacc_ = Do_;                                                          \
    }

#define STOREU(u0_, u1_, u2_, u3_, p_)                                        \
    {                                                                         \
        uint4 A_, Bv_;                                                        \
        A_.x = pk2(u0_[0], u1_[0]); A_.y = pk2(u2_[0], u3_[0]);               \
        A_.z = pk2(u0_[1], u1_[1]); A_.w = pk2(u2_[1], u3_[1]);               \
        Bv_.x = pk2(u0_[2], u1_[2]); Bv_.y = pk2(u2_[2], u3_[2]);             \
        Bv_.z = pk2(u0_[3], u1_[3]); Bv_.w = pk2(u2_[3], u3_[3]);             \
        ushort* ub_ = uhat + (((size_t)l * P + (p_)) * B + cc) * V + kb * 16; \
        *reinterpret_cast<uint4*>(ub_) = A_;                                  \
        *reinterpret_cast<uint4*>(ub_ + 8) = Bv_;                             \
    }

#pragma unroll
    for (int i = 0; i < 2; ++i) {
        // x B-frag variants read at use from persistent xstage (saves 16 VGPR)
        FragU axe_, axo_;
        if (lane < 32)
            axe_.u = *reinterpret_cast<const uint4*>(&xstage[w * 4 + 2 * i][lane][0]);
        else
            axe_.u = (uint4){0u, 0u, 0u, 0u};
        if (lane >= 32)
            axo_.u = *reinterpret_cast<const uint4*>(&xstage[w * 4 + 2 * i + 1][lane - 32][0]);
        else
            axo_.u = (uint4){0u, 0u, 0u, 0u};

        f32x4 ue0, ue1, ue2, ue3, uo0, uo1, uo2, uo3;
        ONEG(0, i, cacc0, ue0, uo0);
        ONEG(1, i, cacc1, ue1, uo1);
        ONEG(2, i, cacc2, ue2, uo2);
        ONEG(3, i, cacc3, ue3, uo3);
        const int pe = p0 + w * 4 + 2 * i;
        STOREU(ue0, ue1, ue2, ue3, pe);
        STOREU(uo0, uo1, uo2, uo3, pe + 1);
    }
#undef ONEG
#undef STOREU

    // s0: wave partials -> LDS, block-reduce over waves -> sp0[l][ch][b][sv]
    {
        float* wb = &wred[w][cc][kb * 16];
        float4 q0 = {cacc0[0], cacc1[0], cacc2[0], cacc3[0]};
        float4 q1 = {cacc0[1], cacc1[1], cacc2[1], cacc3[1]};
        float4 q2 = {cacc0[2], cacc1[2], cacc2[2], cacc3[2]};
        float4 q3 = {cacc0[3], cacc1[3], cacc2[3], cacc3[3]};
        *reinterpret_cast<float4*>(wb + 0) = q0;
        *reinterpret_cast<float4*>(wb + 4) = q1;
        *reinterpret_cast<float4*>(wb + 8) = q2;
        *reinterpret_cast<float4*>(wb + 12) = q3;
    }
    __syncthreads();
    {
        const int o = t * 4;           // output quad: b = o>>6, sv = o&63
        const int b = o >> 6, sv = o & 63;
        const float* r0 = &wred[0][b][sv];
        const float* r1 = &wred[1][b][sv];
        const float* r2 = &wred[2][b][sv];
        const float* r3 = &wred[3][b][sv];
        float4 s;
        s.x = r0[0] + r1[0] + r2[0] + r3[0];
        s.y = r0[1] + r1[1] + r2[1] + r3[1];
        s.z = r0[2] + r1[2] + r2[2] + r3[2];
        s.w = r0[3] + r1[3] + r2[3] + r3[3];
        *reinterpret_cast<float4*>(
            sp0 + (((size_t)l * 64 + ch) * 16 + b) * 64 + sv) = s;
    }
}

// ---------------------------------------------------------------------------
// K_v: generic chunk-reduce + squash (sv space). unperm=1 -> write true-v.
// ---------------------------------------------------------------------------
__global__ __launch_bounds__(256) void k_v(const float* __restrict__ sp,
                                           size_t cb, size_t cl, size_t cs,
                                           int nch, float scale, int unperm,
                                           float* __restrict__ vout,
                                           float* __restrict__ norms) {
    const int b = blockIdx.y;
    const int w = threadIdx.x >> 6, lane = threadIdx.x & 63;
    const int l = blockIdx.x * 4 + w;
    const float* p = sp + cb * b + cl * l + lane;
    float s = 0.f;
#pragma unroll 8
    for (int ch = 0; ch < nch; ++ch) s += p[(size_t)ch * cs];
    s *= scale;
    float sq = wsum64(s * s);
    float f = sqrtf(sq) / (1.0f + sq);
    const int vi = unperm ? ((lane & 3) * 16 + (lane >> 4) * 4 + ((lane >> 2) & 3))
                          : lane;
    vout[((size_t)b * L + l) * V + vi] = s * f;
    if (norms && lane == 0) norms[b * L + l] = sq / (1.0f + sq);
}

// ---------------------------------------------------------------------------
// K_bc: block = (ch of 16 p, b), 512 threads. u tile in REGISTERS.
// uhat layout [l][p][b][sv]; all v-space math in sv space (invariant).
// ---------------------------------------------------------------------------
__global__ __launch_bounds__(512, 4) void k_bc(const ushort* __restrict__ uhat,
                                               const float* __restrict__ vv,
                                               float* __restrict__ bbuf,
                                               float* __restrict__ sp,
                                               float* __restrict__ Tsum,
                                               int add_prev, int do_T) {
    const int ch = blockIdx.x, b = blockIdx.y;
    const int p0 = ch * CHBC;
    const int t = threadIdx.x;
    const int w = t >> 6, lane = t & 63;
    const int pl8 = lane >> 3;
    const int vg8 = lane & 7;
    const int l0 = w * 8;

    __shared__ float vsh[L][V];
    __shared__ float bl[CHBC][L + 1];
    __shared__ float twv[8];

    {
        const float4* vvp = reinterpret_cast<const float4*>(vv + (size_t)b * L * V);
        float4* vshp = reinterpret_cast<float4*>(&vsh[0][0]);
#pragma unroll
        for (int i = 0; i < 2; ++i) vshp[t + i * 512] = vvp[t + i * 512];
    }

    const size_t LSTR = (size_t)P * B * V;   // l stride
    ushort8_t ur[8][2];
    {
        const ushort* ubase = uhat + (((size_t)l0 * P + p0 + pl8) * B + b) * V + vg8 * 8;
#pragma unroll
        for (int li = 0; li < 8; ++li) {
#pragma unroll
            for (int ph = 0; ph < 2; ++ph)
                ur[li][ph] = *reinterpret_cast<const ushort8_t*>(
                    ubase + (size_t)li * LSTR + (size_t)ph * 8 * B * V);
        }
    }
    __syncthreads();

#pragma unroll
    for (int li = 0; li < 8; ++li) {
        const int l = l0 + li;
        const float4 va = *reinterpret_cast<const float4*>(&vsh[l][vg8 * 8]);
        const float4 vb = *reinterpret_cast<const float4*>(&vsh[l][vg8 * 8 + 4]);
#pragma unroll
        for (int ph = 0; ph < 2; ++ph) {
            float d;
            d = bf2f(ur[li][ph][0]) * va.x;
            d = fmaf(bf2f(ur[li][ph][1]), va.y, d);
            d = fmaf(bf2f(ur[li][ph][2]), va.z, d);
            d = fmaf(bf2f(ur[li][ph][3]), va.w, d);
            d = fmaf(bf2f(ur[li][ph][4]), vb.x, d);
            d = fmaf(bf2f(ur[li][ph][5]), vb.y, d);
            d = fmaf(bf2f(ur[li][ph][6]), vb.z, d);
            d = fmaf(bf2f(ur[li][ph][7]), vb.w, d);
            d += __shfl_xor(d, 1, 64);
            d += __shfl_xor(d, 2, 64);
            d += __shfl_xor(d, 4, 64);
            if (vg8 == 0) bl[ph * 8 + pl8][l] = d;
        }
    }
    __syncthreads();

    float tloc = 0.f;
#pragma unroll
    for (int pi = 0; pi < 2; ++pi) {
        const int pli = w * 2 + pi;
        const int p = p0 + pli;
        float bv = bl[pli][lane];
        float* bp = bbuf + ((size_t)b * P + p) * L;
        if (add_prev) bv += bp[lane];
        bp[lane] = bv;
        float m = wmax64(bv);
        float e = __expf(bv - m);
        float ssum = wsum64(e);
        float cc = e / ssum;
        bl[pli][lane] = cc;
        if (do_T) tloc += cc * __logf(64.0f * (cc + 1e-12f));
    }
    if (do_T) {
        float dsum = wsum64(tloc);
        if (lane == 0) twv[w] = dsum;
    }
    __syncthreads();
    if (do_T && t == 0) {
        float s8 = twv[0] + twv[1] + twv[2] + twv[3] +
                   twv[4] + twv[5] + twv[6] + twv[7];
        atomicAdd(Tsum, s8 * (1.0f / LN64));
    }

    float* spb = sp + (size_t)(b * NCH_BC + ch) * L * V;
#pragma unroll
    for (int li = 0; li < 8; ++li) {
        const int l = l0 + li;
        const float cA = bl[pl8][l];
        const float cB = bl[8 + pl8][l];
        float4 pa, pb;
        pa.x = cA * bf2f(ur[li][0][0]) + cB * bf2f(ur[li][1][0]);
        pa.y = cA * bf2f(ur[li][0][1]) + cB * bf2f(ur[li][1][1]);
        pa.z = cA * bf2f(ur[li][0][2]) + cB * bf2f(ur[li][1][2]);
        pa.w = cA * bf2f(ur[li][0][3]) + cB * bf2f(ur[li][1][3]);
        pb.x = cA * bf2f(ur[li][0][4]) + cB * bf2f(ur[li][1][4]);
        pb.y = cA * bf2f(ur[li][0][5]) + cB * bf2f(ur[li][1][5]);
        pb.z = cA * bf2f(ur[li][0][6]) + cB * bf2f(ur[li][1][6]);
        pb.w = cA * bf2f(ur[li][0][7]) + cB * bf2f(ur[li][1][7]);
#pragma unroll
        for (int m = 8; m <= 32; m <<= 1) {
            pa.x += __shfl_xor(pa.x, m, 64);
            pa.y += __shfl_xor(pa.y, m, 64);
            pa.z += __shfl_xor(pa.z, m, 64);
            pa.w += __shfl_xor(pa.w, m, 64);
            pb.x += __shfl_xor(pb.x, m, 64);
            pb.y += __shfl_xor(pb.y, m, 64);
            pb.z += __shfl_xor(pb.z, m, 64);
            pb.w += __shfl_xor(pb.w, m, 64);
        }
        if (pl8 == 0) {
            *reinterpret_cast<float4*>(spb + (size_t)l * V + vg8 * 8) = pa;
            *reinterpret_cast<float4*>(spb + (size_t)l * V + vg8 * 8 + 4) = pb;
        }
    }
}

// ---------------------------------------------------------------------------
// K_final: T and D. One block, 64 threads (lane = l).
// ---------------------------------------------------------------------------
__global__ void k_final(const float* __restrict__ Tsum,
                        const float* __restrict__ norms,
                        float* __restrict__ out) {
    const int lane = threadIdx.x & 63;
    float n[B];
    float sum = 0.f;
#pragma unroll
    for (int b = 0; b < B; ++b) { n[b] = norms[b * L + lane]; sum += n[b]; }
    const float mean = sum * (1.0f / B);
    float var = 0.f;
#pragma unroll
    for (int b = 0; b < B; ++b) { float d = n[b] - mean; var = fmaf(d, d, var); }
    var *= (1.0f / B);
    float sd = sqrtf(var);
    float D = wmax64(sd);
    if (lane == 0) {
        out[B * L * V] = Tsum[0] * (1.0f / (B * P));
        out[B * L * V + 1] = D;
    }
}

extern "C" void kernel_launch(void* const* d_in, const int* in_sizes, int n_in,
                              void* d_out, int out_size, void* d_ws, size_t ws_size,
                              hipStream_t stream) {
    const float* x = (const float*)d_in[0];   // (B,P,Q)
    const float* W = (const float*)d_in[1];   // (L,P,V,Q)
    float* out = (float*)d_out;               // v (B,L,V) then T, D

    char* ws = (char*)d_ws;
    ushort* uhat = (ushort*)ws;                        // [l][p][b][sv] bf16 = 128 MB
    size_t off = (size_t)B * L * P * V * 2;
    float* spbuf = (float*)(ws + off);                 // 32 MB region:
    // sp0 [l][64][16][64] (16.7 MB) and sp [b][64][l][sv] (16.7 MB) share it
    off += (size_t)64 * 128 * 16 * 64 * 4;
    float* vbuf  = (float*)(ws + off); off += (size_t)B * L * V * 4;
    float* bbuf  = (float*)(ws + off); off += (size_t)B * P * L * 4;   // 4 MB
    float* norms = (float*)(ws + off); off += (size_t)B * L * 4;
    float* Tsum  = (float*)(ws + off); off += 256;

    hipMemsetAsync(Tsum, 0, sizeof(float), stream);

    // u_hat: compiler-scheduled reg-direct MFMA, VGPR<=128 (16 waves/CU)
    hipLaunchKernelGGL(k_uhat, dim3(64, 64), dim3(256), 0, stream, W, x, uhat, spbuf);
    // v0 = squash((1/64) * reduce sp0)   sp0 idx = l*65536 + ch*1024 + b*64 + sv
    hipLaunchKernelGGL(k_v, dim3(L / 4, B), dim3(256), 0, stream,
                       spbuf, (size_t)64, (size_t)65536, (size_t)1024, 64,
                       1.0f / 64.0f, 0, vbuf, (float*)nullptr);
    // b1 = v0.u ; c1 ; partial s1 -> sp[b][ch][l][sv]
    hipLaunchKernelGGL(k_bc, dim3(NCH_BC, B), dim3(512), 0, stream,
                       uhat, vbuf, bbuf, spbuf, Tsum, 0, 0);
    // v1 (sv space)
    hipLaunchKernelGGL(k_v, dim3(L / 4, B), dim3(256), 0, stream,
                       spbuf, (size_t)NCH_BC * L * V, (size_t)V, (size_t)L * V,
                       NCH_BC, 1.0f, 0, vbuf, (float*)nullptr);
    // b2 = b1 + v1.u ; c2 ; T partials ; partial s2
    hipLaunchKernelGGL(k_bc, dim3(NCH_BC, B), dim3(512), 0, stream,
                       uhat, vbuf, bbuf, spbuf, Tsum, 1, 1);
    // v2 -> out (un-permuted to true v), norms
    hipLaunchKernelGGL(k_v, dim3(L / 4, B), dim3(256), 0, stream,
                       spbuf, (size_t)NCH_BC * L * V, (size_t)V, (size_t)L * V,
                       NCH_BC, 1.0f, 1, out, norms);
    hipLaunchKernelGGL(k_final, dim3(1), dim3(64), 0, stream, Tsum, norms, out);
}